// Round 1
// baseline (1294.384 us; speedup 1.0000x reference)
//
#include <hip/hip_runtime.h>

#define N_FEAT 128
#define HID 16

__device__ __forceinline__ int lower_bound_dev(const int* __restrict__ a, int n, int v) {
    int lo = 0, hi = n;
    while (lo < hi) {
        int mid = (lo + hi) >> 1;
        if (a[mid] < v) lo = mid + 1; else hi = mid;
    }
    return lo;
}

// One block per graph. batch[] is sorted, so graph g owns a contiguous node
// range found by binary search. Algebraic simplifications:
//   graph_pred = mean(dot(x_i, W_base)) + b_base            (W_base is linear)
//   clock_pooled = mean(relu(cp_i*W1+b1)) @ W2 + b2         (@W2+b2 is affine)
// so the streaming phase only needs 1 scalar + 16 relu accumulators per node.
__global__ __launch_bounds__(256) void clock_gnn_kernel(
    const float* __restrict__ x,
    const float* __restrict__ cp,
    const int* __restrict__ batch,
    const float* __restrict__ W_base,
    const float* __restrict__ b_base,
    const float* __restrict__ W1,
    const float* __restrict__ b1,
    const float* __restrict__ W2,
    const float* __restrict__ b2,
    const float* __restrict__ W3,
    const float* __restrict__ b3,
    const float* __restrict__ W4,
    const float* __restrict__ b4,
    float* __restrict__ out,
    int n_nodes)
{
    const int g = blockIdx.x;
    const int tid = threadIdx.x;

    __shared__ int   s_range[2];
    __shared__ float s_dot[4];
    __shared__ float s_u[4][HID];
    __shared__ float s_mean_u[HID];
    __shared__ float s_comb[HID + 1];

    if (tid == 0) {
        s_range[0] = lower_bound_dev(batch, n_nodes, g);
        s_range[1] = lower_bound_dev(batch, n_nodes, g + 1);
    }
    __syncthreads();
    const int start = s_range[0];
    const int end   = s_range[1];
    const float cnt = fmaxf((float)(end - start), 1.0f);

    // ---------- Phase A: sum_i dot(x_i, W_base) over the segment ----------
    // 32 lanes cover one 128-float row via float4; 8 row-slots per block-iter.
    const int q = tid & 31;   // which float4 of the row
    const int r = tid >> 5;   // row slot 0..7
    const float4 wb = ((const float4*)W_base)[q];
    float acc = 0.f;

    int n = start + r;
    for (; n + 24 < end; n += 32) {  // 4 rows in flight per thread
        float4 a0 = ((const float4*)(x + (size_t)(n     ) * N_FEAT))[q];
        float4 a1 = ((const float4*)(x + (size_t)(n +  8) * N_FEAT))[q];
        float4 a2 = ((const float4*)(x + (size_t)(n + 16) * N_FEAT))[q];
        float4 a3 = ((const float4*)(x + (size_t)(n + 24) * N_FEAT))[q];
        acc = fmaf(a0.x, wb.x, acc); acc = fmaf(a0.y, wb.y, acc);
        acc = fmaf(a0.z, wb.z, acc); acc = fmaf(a0.w, wb.w, acc);
        acc = fmaf(a1.x, wb.x, acc); acc = fmaf(a1.y, wb.y, acc);
        acc = fmaf(a1.z, wb.z, acc); acc = fmaf(a1.w, wb.w, acc);
        acc = fmaf(a2.x, wb.x, acc); acc = fmaf(a2.y, wb.y, acc);
        acc = fmaf(a2.z, wb.z, acc); acc = fmaf(a2.w, wb.w, acc);
        acc = fmaf(a3.x, wb.x, acc); acc = fmaf(a3.y, wb.y, acc);
        acc = fmaf(a3.z, wb.z, acc); acc = fmaf(a3.w, wb.w, acc);
    }
    for (; n < end; n += 8) {
        float4 a0 = ((const float4*)(x + (size_t)n * N_FEAT))[q];
        acc = fmaf(a0.x, wb.x, acc); acc = fmaf(a0.y, wb.y, acc);
        acc = fmaf(a0.z, wb.z, acc); acc = fmaf(a0.w, wb.w, acc);
    }

    // ---------- Phase B: sum_i relu(cp_i * W1 + b1) ----------
    float w1r[HID], b1r[HID], uacc[HID];
    #pragma unroll
    for (int j = 0; j < HID; ++j) { w1r[j] = W1[j]; b1r[j] = b1[j]; uacc[j] = 0.f; }
    for (int i = start + tid; i < end; i += 256) {
        float c = cp[i];
        #pragma unroll
        for (int j = 0; j < HID; ++j)
            uacc[j] += fmaxf(fmaf(c, w1r[j], b1r[j]), 0.f);
    }

    // ---------- wave-level reductions (wave = 64 lanes) ----------
    #pragma unroll
    for (int off = 32; off > 0; off >>= 1) acc += __shfl_down(acc, off);
    #pragma unroll
    for (int j = 0; j < HID; ++j) {
        #pragma unroll
        for (int off = 32; off > 0; off >>= 1) uacc[j] += __shfl_down(uacc[j], off);
    }

    const int wave = tid >> 6;
    const int lane = tid & 63;
    if (lane == 0) {
        s_dot[wave] = acc;
        #pragma unroll
        for (int j = 0; j < HID; ++j) s_u[wave][j] = uacc[j];
    }
    __syncthreads();

    // ---------- per-graph epilogue ----------
    if (tid == 0) {
        float t = s_dot[0] + s_dot[1] + s_dot[2] + s_dot[3];
        s_comb[0] = t / cnt + b_base[0];          // graph_pred
    }
    if (tid < HID) {
        float t = s_u[0][tid] + s_u[1][tid] + s_u[2][tid] + s_u[3][tid];
        s_mean_u[tid] = t / cnt;
    }
    __syncthreads();
    if (tid < HID) {
        float v = b2[tid];
        #pragma unroll
        for (int k = 0; k < HID; ++k) v = fmaf(s_mean_u[k], W2[k * HID + tid], v);
        s_comb[1 + tid] = v;                      // clock_pooled @ W2 + b2
    }
    __syncthreads();

    if (tid < 64) {                               // wave 0 only, all lanes active
        float p = 0.f;
        if (tid < 32) {
            const int m = tid;
            float a = b3[m];
            #pragma unroll
            for (int rr = 0; rr < HID + 1; ++rr)
                a = fmaf(s_comb[rr], W3[rr * 32 + m], a);
            a = fmaxf(a, 0.f);
            p = a * W4[m];
        }
        #pragma unroll
        for (int off = 32; off > 0; off >>= 1) p += __shfl_down(p, off);
        if (tid == 0) out[g] = p + b4[0];
    }
}

extern "C" void kernel_launch(void* const* d_in, const int* in_sizes, int n_in,
                              void* d_out, int out_size, void* d_ws, size_t ws_size,
                              hipStream_t stream) {
    const float* x      = (const float*)d_in[0];
    const float* cp     = (const float*)d_in[1];
    const int*   batch  = (const int*)  d_in[2];
    const float* W_base = (const float*)d_in[3];
    const float* b_base = (const float*)d_in[4];
    const float* W1     = (const float*)d_in[5];
    const float* b1     = (const float*)d_in[6];
    const float* W2     = (const float*)d_in[7];
    const float* b2     = (const float*)d_in[8];
    const float* W3     = (const float*)d_in[9];
    const float* b3     = (const float*)d_in[10];
    const float* W4     = (const float*)d_in[11];
    const float* b4     = (const float*)d_in[12];
    float* out = (float*)d_out;

    const int n_nodes  = in_sizes[2];   // batch has one entry per node
    const int n_graphs = out_size;      // [B, 1] output

    clock_gnn_kernel<<<n_graphs, 256, 0, stream>>>(
        x, cp, batch, W_base, b_base, W1, b1, W2, b2, W3, b3, W4, b4,
        out, n_nodes);
}